// Round 3
// baseline (1959.344 us; speedup 1.0000x reference)
//
#include <hip/hip_runtime.h>
#include <hip/hip_cooperative_groups.h>
#include <hip/hip_bf16.h>
#include <math.h>

namespace cg = cooperative_groups;
using bf16 = __hip_bfloat16;

#define H_IMG 128
#define W_IMG 128
#define C_IN  200
#define NCLS  16
#define N0    16384
#define N1    4096
#define N2    1024
#define KNB   16
#define EPS   1e-5f
#define SLOPE 0.01f

__device__ __forceinline__ float leaky(float v) { return v >= 0.f ? v : SLOPE * v; }

__device__ __forceinline__ float ldw(const void* p, long i, int fl) {
    return fl ? ((const float*)p)[i] : __bfloat162float(((const bf16*)p)[i]);
}

__device__ __forceinline__ float4 ld4f(const float* p, long i) {
    return *reinterpret_cast<const float4*>(p + i);
}
__device__ __forceinline__ float4 ld4b(const bf16* p, long i) {
    const ushort4 u = *reinterpret_cast<const ushort4*>(reinterpret_cast<const unsigned short*>(p) + i);
    float4 r;
    r.x = __uint_as_float((unsigned)u.x << 16);
    r.y = __uint_as_float((unsigned)u.y << 16);
    r.z = __uint_as_float((unsigned)u.z << 16);
    r.w = __uint_as_float((unsigned)u.w << 16);
    return r;
}
template <typename T> __device__ __forceinline__ float4 ld4(const T* p, long i);
template <> __device__ __forceinline__ float4 ld4<float>(const float* p, long i) { return ld4f(p, i); }
template <> __device__ __forceinline__ float4 ld4<bf16>(const bf16* p, long i) { return ld4b(p, i); }

// ---------------- GEMM cores ----------------
template <typename T, int ACT>
__device__ __forceinline__ void gemm4_body(const T* __restrict__ In, const float* __restrict__ Wf,
                                           const float* __restrict__ Bf, float* __restrict__ Out,
                                           int Ci, int Co, int blk) {
    int tid = blk * 256 + threadIdx.x;
    int Coq = Co >> 2;
    int n = tid / Coq;
    int j4 = (tid - n * Coq) << 2;
    const T* in = In + (long)n * Ci;
    const float* wp = Wf + j4;
    float4 acc = *reinterpret_cast<const float4*>(Bf + j4);
    for (int c = 0; c < Ci; c += 4) {
        float4 xv = ld4(in, c);
        float4 w0 = *reinterpret_cast<const float4*>(wp + (long)c * Co);
        float4 w1 = *reinterpret_cast<const float4*>(wp + (long)(c + 1) * Co);
        float4 w2 = *reinterpret_cast<const float4*>(wp + (long)(c + 2) * Co);
        float4 w3 = *reinterpret_cast<const float4*>(wp + (long)(c + 3) * Co);
        acc.x += xv.x * w0.x; acc.y += xv.x * w0.y; acc.z += xv.x * w0.z; acc.w += xv.x * w0.w;
        acc.x += xv.y * w1.x; acc.y += xv.y * w1.y; acc.z += xv.y * w1.z; acc.w += xv.y * w1.w;
        acc.x += xv.z * w2.x; acc.y += xv.z * w2.y; acc.z += xv.z * w2.z; acc.w += xv.z * w2.w;
        acc.x += xv.w * w3.x; acc.y += xv.w * w3.y; acc.z += xv.w * w3.z; acc.w += xv.w * w3.w;
    }
    if (ACT) { acc.x = leaky(acc.x); acc.y = leaky(acc.y); acc.z = leaky(acc.z); acc.w = leaky(acc.w); }
    *reinterpret_cast<float4*>(Out + (long)n * Co + j4) = acc;
}

// dual-source (virtual concat): c<SPLIT from InA (row n>>2), else InB (row n)
template <int ACT, int SPLIT>
__device__ __forceinline__ void gemm4cat_body(const float* __restrict__ InA, int sA,
                                              const float* __restrict__ InB, int sB,
                                              const float* __restrict__ Wf, const float* __restrict__ Bf,
                                              float* __restrict__ Out, int Ci, int Co, int blk) {
    int tid = blk * 256 + threadIdx.x;
    int Coq = Co >> 2;
    int n = tid / Coq;
    int j4 = (tid - n * Coq) << 2;
    const float* ia = InA + (long)(n >> 2) * sA;
    const float* ib = InB + (long)n * sB;
    const float* wp = Wf + j4;
    float4 acc = *reinterpret_cast<const float4*>(Bf + j4);
    for (int c = 0; c < Ci; c += 4) {
        float4 xv = (c < SPLIT) ? *reinterpret_cast<const float4*>(ia + c)
                                : *reinterpret_cast<const float4*>(ib + (c - SPLIT));
        float4 w0 = *reinterpret_cast<const float4*>(wp + (long)c * Co);
        float4 w1 = *reinterpret_cast<const float4*>(wp + (long)(c + 1) * Co);
        float4 w2 = *reinterpret_cast<const float4*>(wp + (long)(c + 2) * Co);
        float4 w3 = *reinterpret_cast<const float4*>(wp + (long)(c + 3) * Co);
        acc.x += xv.x * w0.x; acc.y += xv.x * w0.y; acc.z += xv.x * w0.z; acc.w += xv.x * w0.w;
        acc.x += xv.y * w1.x; acc.y += xv.y * w1.y; acc.z += xv.y * w1.z; acc.w += xv.y * w1.w;
        acc.x += xv.z * w2.x; acc.y += xv.z * w2.y; acc.z += xv.z * w2.z; acc.w += xv.z * w2.w;
        acc.x += xv.w * w3.x; acc.y += xv.w * w3.y; acc.z += xv.w * w3.z; acc.w += xv.w * w3.w;
    }
    if (ACT) { acc.x = leaky(acc.x); acc.y = leaky(acc.y); acc.z = leaky(acc.z); acc.w = leaky(acc.w); }
    *reinterpret_cast<float4*>(Out + (long)n * Co + j4) = acc;
}

// ---------------- alpha/beta from partials into LDS ----------------
__device__ __forceinline__ void alphabeta_ld(const float2* __restrict__ partA, int npA, int splitC,
                                             const float2* __restrict__ partB, int npB,
                                             int Ci, float Pinv, const void* g, const void* b_,
                                             int fl, float* al, float* be) {
    int t = threadIdx.x;
    if (t < Ci) {
        const float2* src = (t < splitC) ? partA + (long)t * npA : partB + (long)(t - splitC) * npB;
        int np = (t < splitC) ? npA : npB;
        float s = 0.f, s2 = 0.f;
        const float4* p4 = (const float4*)src;
        for (int i = 0; i < (np >> 1); i++) { float4 v = p4[i]; s += v.x + v.z; s2 += v.y + v.w; }
        float mu = s * Pinv;
        float var = s2 * Pinv - mu * mu;
        float a = rsqrtf(var + EPS) * ldw(g, t, fl);
        al[t] = a;
        be[t] = ldw(b_, t, fl) - mu * a;
    }
    __syncthreads();
}

// ---------------- fold one output column j ----------------
__device__ __forceinline__ void foldL(int j, const void* Wsrc, const void* bias,
                                      const float* al, const float* be,
                                      float* __restrict__ Wf, float* __restrict__ Bf,
                                      int Ci, int Co, int omajor, int fl, float* red) {
    int t = threadIdx.x;
    float acc = 0.f;
    for (int c = t; c < Ci; c += 256) {
        long idx = omajor ? (long)j * Ci + c : (long)c * Co + j;
        float w = ldw(Wsrc, idx, fl);
        Wf[(long)c * Co + j] = w * al[c];
        acc += w * be[c];
    }
    red[t] = acc; __syncthreads();
    for (int k = 128; k > 0; k >>= 1) { if (t < k) red[t] += red[t + k]; __syncthreads(); }
    if (t == 0) Bf[j] = ldw(bias, j, fl) + red[0];
    __syncthreads();   // protect red before next unit reuses it
}

// ---------------- depthwise 5x5 unit (weights pre-staged in LDS) ----------------
__device__ __forceinline__ void dw_load(const void* dwp, const void* dbp, float* wl, float* bl, int fl) {
    int t = threadIdx.x;
    for (int e = t; e < 25 * 128; e += 256) {
        int o = e / 25, i = e - o * 25;
        wl[i * 128 + o] = ldw(dwp, e, fl);
    }
    if (t < 128) bl[t] = ldw(dbp, t, fl);
    __syncthreads();
}

__device__ __forceinline__ void dw_unit(int blk, const float* __restrict__ In, float* __restrict__ Out,
                                        const float* wl, const float* bl) {
    int tid = blk * 256 + threadIdx.x;
    int o0 = (tid & 31) << 2;
    int p = tid >> 5;
    int h = p >> 7, w = p & 127;
    float4 acc = *reinterpret_cast<const float4*>(&bl[o0]);
#pragma unroll
    for (int dh = -2; dh <= 2; dh++) {
        int hh = h + dh;
        if ((unsigned)hh >= (unsigned)H_IMG) continue;
#pragma unroll
        for (int dv = -2; dv <= 2; dv++) {
            int ww = w + dv;
            if ((unsigned)ww >= (unsigned)W_IMG) continue;
            float4 iv = *reinterpret_cast<const float4*>(&In[(long)(((hh << 7) + ww) << 7) + o0]);
            float4 wv = *reinterpret_cast<const float4*>(&wl[((dh + 2) * 5 + (dv + 2)) * 128 + o0]);
            acc.x += iv.x * wv.x; acc.y += iv.y * wv.y; acc.z += iv.z * wv.z; acc.w += iv.w * wv.w;
        }
    }
    acc.x = leaky(acc.x); acc.y = leaky(acc.y); acc.z = leaky(acc.z); acc.w = leaky(acc.w);
    *reinterpret_cast<float4*>(&Out[(long)p * 128 + o0]) = acc;
}

// ---------------- attention unit (4 rows per unit) ----------------
// MODE 0: co=64, emits H2b + partP (pooled) + partS (row stats)
// MODE 1/2: emits 4x-weighted partS
template <int MODE>
__device__ __forceinline__ void attn_unit(int b, const float* __restrict__ th, const float* __restrict__ outm,
                                          const int* __restrict__ nbr, float* __restrict__ dst, int co,
                                          float* __restrict__ H2b, float2* __restrict__ partP,
                                          float2* __restrict__ partS, int snp, float* sm) {
    int wid = threadIdx.x >> 6, l = threadIdx.x & 63;
    int n = b * 4 + wid;
    float r0 = th[(long)n * 128 + l];
    float r1 = th[(long)n * 128 + 64 + l];
    int mk[KNB];
    float av[KNB];
#pragma unroll
    for (int k = 0; k < KNB; k++) {
        int m = nbr[n * KNB + k];
        mk[k] = m;
        float v = r0 * th[(long)m * 128 + l] + r1 * th[(long)m * 128 + 64 + l];
#pragma unroll
        for (int off = 32; off > 0; off >>= 1) v += __shfl_xor(v, off, 64);
        av[k] = 1.f / (1.f + expf(-v));
    }
    float amax = av[0];
#pragma unroll
    for (int k = 1; k < KNB; k++) amax = fmaxf(amax, av[k]);
    float den = 0.f;
#pragma unroll
    for (int k = 0; k < KNB; k++) { av[k] = expf(av[k] - amax); den += av[k]; }
    float rden = 1.f / den;
    float val = 0.f;
    if (l < co) {
        float acc = 0.f;
#pragma unroll
        for (int k = 0; k < KNB; k++) acc += av[k] * outm[(long)mk[k] * co + l];
        val = leaky(acc * rden);
        dst[(long)n * co + l] = val;
    }
    sm[wid * 64 + l] = (l < co) ? val : 0.f;
    __syncthreads();
    if (wid == 0 && l < co) {
        float a = sm[l], bb = sm[64 + l], c = sm[128 + l], d = sm[192 + l];
        float su = a + bb + c + d;
        float sq = a * a + bb * bb + c * c + d * d;
        if (MODE == 0) {
            float h = 0.25f * su;
            H2b[(long)b * 64 + l] = h;
            partP[(long)l * snp + b] = make_float2(h, h * h);
            partS[(long)l * snp + b] = make_float2(su, sq);
        } else {
            partS[(long)l * snp + b] = make_float2(4.f * su, 4.f * sq);
        }
    }
    __syncthreads();   // protect sm before next unit
}

// ================= args =================
struct MegaArgs {
    const void* x;
    const int* nbr_a; const int* nbr_b;
    const void *hg, *hb, *hpw, *hpb, *hdw, *hdb;
    const void *e0_g, *e0_b, *e0_wt, *e0_bt, *e0_wo, *e0_bo;
    const void *e1_g, *e1_b, *e1_wt, *e1_bt, *e1_wo, *e1_bo;
    const void *d0_g, *d0_b, *d0_wt, *d0_bt, *d0_wo, *d0_bo;
    const void *tg, *tb, *tpw, *tpb, *tdw, *tdb, *wsw, *wb;
    float *WF1, *BF1, *WF2, *BF2;
    float2 *P_HEAD, *P_E0, *P_E1, *P_D0a, *P_D0b, *P_Ta, *P_Tb;
    float *R0, *R1, *T1, *H1b, *THb, *OUTb, *ENC1, *H2b, *HDb, *HDEC;
    void* out;
};

#define FOR_B(NB) for (int b = (int)blockIdx.x; b < (NB); b += G)

__global__ __launch_bounds__(256, 4) void mega_kernel(MegaArgs a) {
    cg::grid_group grid = cg::this_grid();
    const int G = (int)gridDim.x;
    const int t = threadIdx.x;

    __shared__ float s_al[256];
    __shared__ float s_be[256];
    __shared__ float s_red[256];
    __shared__ float s_dww[25 * 128];
    __shared__ float s_dwb[128];
    __shared__ float s_cls[2048];
    __shared__ float s_sm[256];
    __shared__ int s_cnt;

    // ---- dtype detect (per block, result kept in register) ----
    if (t == 0) s_cnt = 0;
    __syncthreads();
    {
        const unsigned short* xu = (const unsigned short*)a.x;
        int cnt = 0;
        for (int i = t; i < 4096; i += 256) {
            unsigned short e = (unsigned short)((xu[i] >> 7) & 0xFF);
            if (e >= 0xC0) cnt++;
        }
#pragma unroll
        for (int off = 32; off > 0; off >>= 1) cnt += __shfl_xor(cnt, off, 64);
        if ((t & 63) == 0) atomicAdd(&s_cnt, cnt);
    }
    __syncthreads();
    const int fl = (s_cnt > 32) ? 1 : 0;

    // ---- S1: head BN stage A ----
    FOR_B(256) {
        if (t < C_IN) {
            float s = 0.f, s2 = 0.f;
            if (fl) {
                const float* p = (const float*)a.x + (long)b * 64 * C_IN + t;
                for (int r = 0; r < 64; r++) { float v = p[(long)r * C_IN]; s += v; s2 += v * v; }
            } else {
                const bf16* p = (const bf16*)a.x + (long)b * 64 * C_IN + t;
                for (int r = 0; r < 64; r++) { float v = __bfloat162float(p[(long)r * C_IN]); s += v; s2 += v * v; }
            }
            a.P_HEAD[(long)t * 256 + b] = make_float2(s, s2);
        }
    }
    grid.sync();

    // ---- S2: head BN reduce + fold 1x1 (omajor) ----
    alphabeta_ld(a.P_HEAD, 256, 256, a.P_HEAD, 256, C_IN, 1.f / (float)N0, a.hg, a.hb, fl, s_al, s_be);
    FOR_B(128) foldL(b, a.hpw, a.hpb, s_al, s_be, a.WF1, a.BF1, C_IN, 128, 1, fl, s_red);
    grid.sync();

    // ---- S3: head pointwise GEMM + leaky -> R0 ----
    if (fl) { FOR_B(2048) gemm4_body<float, 1>((const float*)a.x, a.WF1, a.BF1, a.R0, C_IN, 128, b); }
    else    { FOR_B(2048) gemm4_body<bf16, 1>((const bf16*)a.x, a.WF1, a.BF1, a.R0, C_IN, 128, b); }
    grid.sync();

    // ---- S4: head depthwise -> R1 (enc0) ----
    dw_load(a.hdw, a.hdb, s_dww, s_dwb, fl);
    FOR_B(2048) dw_unit(b, a.R0, a.R1, s_dww, s_dwb);
    grid.sync();

    // ---- S5: pool4 + e0 stats + tail raw stats ----
    FOR_B(256) {
        if (t < 128) {
            float s = 0.f, s2 = 0.f, rs = 0.f, rs2 = 0.f;
            const float* base = a.R1 + (long)b * 64 * 128 + t;
            for (int r = 0; r < 16; r++) {
                const float* rp = base + (long)r * 512;
                float v0 = rp[0], v1 = rp[128], v2 = rp[256], v3 = rp[384];
                float h = 0.25f * (v0 + v1 + v2 + v3);
                a.H1b[(long)(b * 16 + r) * 128 + t] = h;
                s += h; s2 += h * h;
                rs += v0 + v1 + v2 + v3;
                rs2 += v0 * v0 + v1 * v1 + v2 * v2 + v3 * v3;
            }
            a.P_E0[(long)t * 256 + b] = make_float2(s, s2);
            a.P_Tb[(long)t * 256 + b] = make_float2(rs, rs2);
        }
    }
    grid.sync();

    // ---- S6: e0 BN reduce + fold wt/wo ----
    alphabeta_ld(a.P_E0, 256, 128, a.P_E0, 256, 128, 1.f / (float)N1, a.e0_g, a.e0_b, fl, s_al, s_be);
    FOR_B(192) {
        if (b < 128) foldL(b, a.e0_wt, a.e0_bt, s_al, s_be, a.WF1, a.BF1, 128, 128, 0, fl, s_red);
        else         foldL(b - 128, a.e0_wo, a.e0_bo, s_al, s_be, a.WF2, a.BF2, 128, 64, 0, fl, s_red);
    }
    grid.sync();

    // ---- S7: e0 theta+out GEMMs ----
    FOR_B(768) {
        if (b < 512) gemm4_body<float, 0>(a.H1b, a.WF1, a.BF1, a.THb, 128, 128, b);
        else         gemm4_body<float, 0>(a.H1b, a.WF2, a.BF2, a.OUTb, 128, 64, b - 512);
    }
    grid.sync();

    // ---- S8: e0 attention -> ENC1 (+H2b, e1 stats, d0 stats ch32..95) ----
    FOR_B(1024) attn_unit<0>(b, a.THb, a.OUTb, a.nbr_a, a.ENC1, 64, a.H2b, a.P_E1, a.P_D0b, 1024, s_sm);
    grid.sync();

    // ---- S9: e1 BN reduce + fold ----
    alphabeta_ld(a.P_E1, 1024, 64, a.P_E1, 1024, 64, 1.f / (float)N2, a.e1_g, a.e1_b, fl, s_al, s_be);
    FOR_B(160) {
        if (b < 128) foldL(b, a.e1_wt, a.e1_bt, s_al, s_be, a.WF1, a.BF1, 64, 128, 0, fl, s_red);
        else         foldL(b - 128, a.e1_wo, a.e1_bo, s_al, s_be, a.WF2, a.BF2, 64, 32, 0, fl, s_red);
    }
    grid.sync();

    // ---- S10: e1 GEMMs ----
    FOR_B(160) {
        if (b < 128) gemm4_body<float, 0>(a.H2b, a.WF1, a.BF1, a.THb, 64, 128, b);
        else         gemm4_body<float, 0>(a.H2b, a.WF2, a.BF2, a.OUTb, 64, 32, b - 128);
    }
    grid.sync();

    // ---- S11: e1 attention -> HDb (+d0 stats ch0..31, x4) ----
    FOR_B(256) attn_unit<1>(b, a.THb, a.OUTb, a.nbr_b, a.HDb, 32, nullptr, nullptr, a.P_D0a, 256, s_sm);
    grid.sync();

    // ---- S12: d0 BN reduce + fold ----
    alphabeta_ld(a.P_D0a, 256, 32, a.P_D0b, 1024, 96, 1.f / (float)N1, a.d0_g, a.d0_b, fl, s_al, s_be);
    FOR_B(192) {
        if (b < 128) foldL(b, a.d0_wt, a.d0_bt, s_al, s_be, a.WF1, a.BF1, 96, 128, 0, fl, s_red);
        else         foldL(b - 128, a.d0_wo, a.d0_bo, s_al, s_be, a.WF2, a.BF2, 96, 64, 0, fl, s_red);
    }
    grid.sync();

    // ---- S13: d0 GEMMs on virtual concat [HDb | ENC1] ----
    FOR_B(768) {
        if (b < 512) gemm4cat_body<0, 32>(a.HDb, 32, a.ENC1, 64, a.WF1, a.BF1, a.THb, 96, 128, b);
        else         gemm4cat_body<0, 32>(a.HDb, 32, a.ENC1, 64, a.WF2, a.BF2, a.OUTb, 96, 64, b - 512);
    }
    grid.sync();

    // ---- S14: d0 attention -> HDEC (+tail stats ch0..63, x4) ----
    FOR_B(1024) attn_unit<2>(b, a.THb, a.OUTb, a.nbr_a, a.HDEC, 64, nullptr, nullptr, a.P_Ta, 1024, s_sm);
    grid.sync();

    // ---- S15: tail BN reduce + fold (omajor) ----
    alphabeta_ld(a.P_Ta, 1024, 64, a.P_Tb, 256, 192, 1.f / (float)N0, a.tg, a.tb, fl, s_al, s_be);
    FOR_B(128) foldL(b, a.tpw, a.tpb, s_al, s_be, a.WF1, a.BF1, 192, 128, 1, fl, s_red);
    grid.sync();

    // ---- S16: tail pointwise GEMM + leaky on virtual concat [HDEC | enc0] -> T1 ----
    FOR_B(2048) gemm4cat_body<1, 64>(a.HDEC, 64, a.R1, 128, a.WF1, a.BF1, a.T1, 192, 128, b);
    grid.sync();

    // ---- S17: tail depthwise -> R0 ----
    dw_load(a.tdw, a.tdb, s_dww, s_dwb, fl);
    FOR_B(2048) dw_unit(b, a.T1, a.R0, s_dww, s_dwb);
    grid.sync();

    // ---- S18: classifier + softmax ----
    for (int e = t; e < 2048; e += 256) s_cls[e] = ldw(a.wsw, e, fl);
    __syncthreads();
    FOR_B(1024) {
        int tid = b * 256 + t;
        int p = tid >> 4;
        int j = tid & 15;
        float acc = ldw(a.wb, j, fl);
        const float* fp = a.R0 + (long)p * 128;
#pragma unroll 8
        for (int c = 0; c < 128; c += 4) {
            float4 fv = *reinterpret_cast<const float4*>(fp + c);
            acc += fv.x * s_cls[c * 16 + j] + fv.y * s_cls[(c + 1) * 16 + j]
                 + fv.z * s_cls[(c + 2) * 16 + j] + fv.w * s_cls[(c + 3) * 16 + j];
        }
        float m = acc;
#pragma unroll
        for (int s = 8; s > 0; s >>= 1) m = fmaxf(m, __shfl_xor(m, s, 16));
        float e = expf(acc - m);
        float d = e;
#pragma unroll
        for (int s = 8; s > 0; s >>= 1) d += __shfl_xor(d, s, 16);
        float r = e / d;
        if (fl) ((float*)a.out)[tid] = r;
        else ((bf16*)a.out)[tid] = __float2bfloat16(r);
    }
}

// ================= host side =================
extern "C" void kernel_launch(void* const* d_in, const int* in_sizes, int n_in,
                              void* d_out, int out_size, void* d_ws, size_t ws_size,
                              hipStream_t stream) {
    bool dict = (in_sizes[1] > 1000000);
    int I_x, I_nbr_a, I_nbr_b, I_hg, I_ws, I_e0, I_e1, I_d0, I_tg;
    if (dict) {
        I_x = 0; I_nbr_a = 5; I_nbr_b = 6; I_hg = 7; I_e0 = 13; I_e1 = 19; I_d0 = 25; I_tg = 31; I_ws = 37;
    } else {
        I_x = 0; I_hg = 1; I_e0 = 7; I_e1 = 13; I_d0 = 19; I_tg = 25; I_ws = 31; I_nbr_a = 37; I_nbr_b = 38;
    }

    MegaArgs a;
    a.x     = d_in[I_x];
    a.nbr_a = (const int*)d_in[I_nbr_a];
    a.nbr_b = (const int*)d_in[I_nbr_b];
    a.hg  = d_in[I_hg + 0]; a.hb  = d_in[I_hg + 1]; a.hpw = d_in[I_hg + 2];
    a.hpb = d_in[I_hg + 3]; a.hdw = d_in[I_hg + 4]; a.hdb = d_in[I_hg + 5];
    a.e0_g = d_in[I_e0 + 0]; a.e0_b = d_in[I_e0 + 1]; a.e0_wt = d_in[I_e0 + 2];
    a.e0_bt = d_in[I_e0 + 3]; a.e0_wo = d_in[I_e0 + 4]; a.e0_bo = d_in[I_e0 + 5];
    a.e1_g = d_in[I_e1 + 0]; a.e1_b = d_in[I_e1 + 1]; a.e1_wt = d_in[I_e1 + 2];
    a.e1_bt = d_in[I_e1 + 3]; a.e1_wo = d_in[I_e1 + 4]; a.e1_bo = d_in[I_e1 + 5];
    a.d0_g = d_in[I_d0 + 0]; a.d0_b = d_in[I_d0 + 1]; a.d0_wt = d_in[I_d0 + 2];
    a.d0_bt = d_in[I_d0 + 3]; a.d0_wo = d_in[I_d0 + 4]; a.d0_bo = d_in[I_d0 + 5];
    a.tg  = d_in[I_tg + 0]; a.tb  = d_in[I_tg + 1]; a.tpw = d_in[I_tg + 2];
    a.tpb = d_in[I_tg + 3]; a.tdw = d_in[I_tg + 4]; a.tdb = d_in[I_tg + 5];
    a.wsw = d_in[I_ws + 0]; a.wb  = d_in[I_ws + 1];

    float* W = (float*)d_ws;
    a.WF1 = W + 0;
    a.BF1 = W + 25600;
    a.WF2 = W + 25728;
    a.BF2 = W + 33920;
    a.P_HEAD = (float2*)(W + 34048);
    a.P_E0   = (float2*)(W + 136448);
    a.P_E1   = (float2*)(W + 201984);
    a.P_D0a  = (float2*)(W + 333056);
    a.P_D0b  = (float2*)(W + 349440);
    a.P_Ta   = (float2*)(W + 480512);
    a.P_Tb   = (float2*)(W + 611584);
    a.R0   = W + 677120;
    a.R1   = a.R0 + (long)N0 * 128;
    a.T1   = a.R1 + (long)N0 * 128;
    a.H1b  = a.T1 + (long)N0 * 128;
    a.THb  = a.H1b + (long)N1 * 128;
    a.OUTb = a.THb + (long)N1 * 128;
    a.ENC1 = a.OUTb + (long)N1 * 64;
    a.H2b  = a.ENC1 + (long)N1 * 64;
    a.HDb  = a.H2b + (long)N2 * 64;
    a.HDEC = a.HDb + (long)N2 * 32;
    a.out  = d_out;

    int maxb = 0;
    hipError_t oe = hipOccupancyMaxActiveBlocksPerMultiprocessor(
        &maxb, reinterpret_cast<const void*>(&mega_kernel), 256, 0);
    if (oe != hipSuccess || maxb < 1) maxb = 2;
    int nblk = maxb * 256;           // 256 CUs on MI355X
    if (nblk > 1024) nblk = 1024;

    void* kargs[] = { (void*)&a };
    hipLaunchCooperativeKernel(reinterpret_cast<const void*>(&mega_kernel),
                               dim3(nblk), dim3(256), kargs, 0, stream);
}

// Round 4
// 949.183 us; speedup vs baseline: 2.0642x; 2.0642x over previous
//
#include <hip/hip_runtime.h>
#include <hip/hip_bf16.h>
#include <math.h>

using bf16 = __hip_bfloat16;

#define H_IMG 128
#define W_IMG 128
#define C_IN  200
#define NCLS  16
#define N0    16384
#define N1    4096
#define N2    1024
#define KNB   16
#define EPS   1e-5f
#define SLOPE 0.01f

__device__ __forceinline__ float ldf(const float* p, long i) { return p[i]; }
__device__ __forceinline__ float ldf(const bf16* p, long i) { return __bfloat162float(p[i]); }
__device__ __forceinline__ float ldw(const void* p, long i, int fl) {
    return fl ? ((const float*)p)[i] : __bfloat162float(((const bf16*)p)[i]);
}
__device__ __forceinline__ float leaky(float v) { return v >= 0.f ? v : SLOPE * v; }

__device__ __forceinline__ float4 ld4(const float* p, long i) {
    return *reinterpret_cast<const float4*>(p + i);
}
__device__ __forceinline__ float4 ld4(const bf16* p, long i) {
    const ushort4 u = *reinterpret_cast<const ushort4*>(reinterpret_cast<const unsigned short*>(p) + i);
    float4 r;
    r.x = __uint_as_float((unsigned)u.x << 16);
    r.y = __uint_as_float((unsigned)u.y << 16);
    r.z = __uint_as_float((unsigned)u.z << 16);
    r.w = __uint_as_float((unsigned)u.w << 16);
    return r;
}

// ---------- per-block dtype detect ----------
__device__ __forceinline__ int block_detect(const unsigned short* __restrict__ x) {
    __shared__ int cnt_s;
    if (threadIdx.x == 0) cnt_s = 0;
    __syncthreads();
    int cnt = 0;
    for (int i = threadIdx.x; i < 4096; i += blockDim.x) {
        unsigned short e = (unsigned short)((x[i] >> 7) & 0xFF);
        if (e >= 0xC0) cnt++;
    }
#pragma unroll
    for (int off = 32; off > 0; off >>= 1) cnt += __shfl_xor(cnt, off, 64);
    if ((threadIdx.x & 63) == 0) atomicAdd(&cnt_s, cnt);
    __syncthreads();
    return cnt_s > 32 ? 1 : 0;
}

// ---------------- S1: head BN stage A (+detect) ----------------
__global__ __launch_bounds__(256) void bnx_kernel(const void* __restrict__ X, float2* __restrict__ part,
                                                  int* __restrict__ dflag) {
    int fl = block_detect((const unsigned short*)X);
    if (blockIdx.x == 0 && threadIdx.x == 0) *dflag = fl;
    int b = blockIdx.x, t = threadIdx.x;
    if (t >= C_IN) return;
    float s = 0.f, s2 = 0.f;
    if (fl) {
        const float* p = (const float*)X + (long)b * 64 * C_IN + t;
        for (int r = 0; r < 64; r++) { float v = p[(long)r * C_IN]; s += v; s2 += v * v; }
    } else {
        const bf16* p = (const bf16*)X + (long)b * 64 * C_IN + t;
        for (int r = 0; r < 64; r++) { float v = __bfloat162float(p[(long)r * C_IN]); s += v; s2 += v * v; }
    }
    part[(long)t * 256 + b] = make_float2(s, s2);
}

// ---------------- alpha/beta from partials into LDS ----------------
__device__ __forceinline__ void alphabeta_ld(const float2* __restrict__ partA, int npA, int splitC,
                                             const float2* __restrict__ partB, int npB,
                                             int Ci, float Pinv, const void* g, const void* b_,
                                             int fl, float* al, float* be) {
    int t = threadIdx.x;
    if (t < Ci) {
        const float2* src = (t < splitC) ? partA + (long)t * npA : partB + (long)(t - splitC) * npB;
        int np = (t < splitC) ? npA : npB;
        float s = 0.f, s2 = 0.f;
        const float4* p4 = (const float4*)src;
        for (int i = 0; i < (np >> 1); i++) { float4 v = p4[i]; s += v.x + v.z; s2 += v.y + v.w; }
        float mu = s * Pinv;
        float var = s2 * Pinv - mu * mu;
        float a = rsqrtf(var + EPS) * ldw(g, t, fl);
        al[t] = a;
        be[t] = ldw(b_, t, fl) - mu * a;
    }
    __syncthreads();
}

__device__ __forceinline__ void foldL(int j, const void* Wsrc, const void* bias,
                                      const float* al, const float* be,
                                      float* __restrict__ Wf, float* __restrict__ Bf,
                                      int Ci, int Co, int omajor, int fl, float* red) {
    int t = threadIdx.x;
    float acc = 0.f;
    for (int c = t; c < Ci; c += 256) {
        long idx = omajor ? (long)j * Ci + c : (long)c * Co + j;
        float w = ldw(Wsrc, idx, fl);
        Wf[(long)c * Co + j] = w * al[c];
        acc += w * be[c];
    }
    red[t] = acc; __syncthreads();
    for (int k = 128; k > 0; k >>= 1) { if (t < k) red[t] += red[t + k]; __syncthreads(); }
    if (t == 0) Bf[j] = ldw(bias, j, fl) + red[0];
}

__global__ __launch_bounds__(256) void bnfold_kernel(const float2* partA, int npA, int splitC,
                                                     const float2* partB, int npB, int P,
                                                     const void* g, const void* b_,
                                                     const void* Wt, const void* bias,
                                                     float* Wf, float* Bf, int Ci, int Co, int omajor,
                                                     const int* dflag) {
    __shared__ float al[256], be[256], red[256];
    int fl = *dflag;
    alphabeta_ld(partA, npA, splitC, partB, npB, Ci, 1.f / (float)P, g, b_, fl, al, be);
    foldL(blockIdx.x, Wt, bias, al, be, Wf, Bf, Ci, Co, omajor, fl, red);
}

__global__ __launch_bounds__(256) void bnfold2_kernel(const float2* partA, int npA, int splitC,
                                                      const float2* partB, int npB, int P,
                                                      const void* g, const void* b_,
                                                      const void* W1, const void* b1,
                                                      const void* W2, const void* b2,
                                                      float* Wf1, float* Bf1, float* Wf2, float* Bf2,
                                                      int Ci, int Co1, int Co2, const int* dflag) {
    __shared__ float al[256], be[256], red[256];
    int fl = *dflag;
    alphabeta_ld(partA, npA, splitC, partB, npB, Ci, 1.f / (float)P, g, b_, fl, al, be);
    int j = blockIdx.x;
    if (j < Co1) foldL(j, W1, b1, al, be, Wf1, Bf1, Ci, Co1, 0, fl, red);
    else         foldL(j - Co1, W2, b2, al, be, Wf2, Bf2, Ci, Co2, 0, fl, red);
}

// ---------------- LDS-tiled GEMM: 16 rows x 128 cols per block ----------------
// CAT=0: In row-major stride CI. CAT=1: c<64 from A2[n>>2][c] (stride 64), else In[n][c-64] (stride 128).
template <typename T, int CI, int KT, int CAT>
__device__ __forceinline__ void gemmT_body(const T* __restrict__ In, const float* __restrict__ A2,
                                           const float* __restrict__ Wf, const float* __restrict__ Bf,
                                           float* __restrict__ Out) {
    __shared__ float wls[KT * 128];
    int t = threadIdx.x;
    int jq = t & 31, rp = t >> 5;
    int n0 = blockIdx.x * 16;
    int r0 = n0 + rp * 2, r1 = r0 + 1;
    float4 a0 = *reinterpret_cast<const float4*>(Bf + jq * 4);
    float4 a1 = a0;
    for (int kt = 0; kt < CI; kt += KT) {
        for (int e = t * 4; e < KT * 128; e += 1024)
            *reinterpret_cast<float4*>(&wls[e]) = *reinterpret_cast<const float4*>(&Wf[(long)kt * 128 + e]);
        __syncthreads();
        for (int cc = 0; cc < KT; cc += 4) {
            int c = kt + cc;
            float4 x0, x1;
            if (CAT) {
                if (c < 64) {
                    x0 = ld4(A2 + (long)(r0 >> 2) * 64, c);
                    x1 = ld4(A2 + (long)(r1 >> 2) * 64, c);
                } else {
                    x0 = ld4((const float*)In + (long)r0 * 128, c - 64);
                    x1 = ld4((const float*)In + (long)r1 * 128, c - 64);
                }
            } else {
                x0 = ld4(In + (long)r0 * CI, c);
                x1 = ld4(In + (long)r1 * CI, c);
            }
            const float* wp = &wls[cc * 128 + jq * 4];
            float4 w0 = *reinterpret_cast<const float4*>(wp);
            float4 w1 = *reinterpret_cast<const float4*>(wp + 128);
            float4 w2 = *reinterpret_cast<const float4*>(wp + 256);
            float4 w3 = *reinterpret_cast<const float4*>(wp + 384);
            a0.x += x0.x * w0.x; a0.y += x0.x * w0.y; a0.z += x0.x * w0.z; a0.w += x0.x * w0.w;
            a1.x += x1.x * w0.x; a1.y += x1.x * w0.y; a1.z += x1.x * w0.z; a1.w += x1.x * w0.w;
            a0.x += x0.y * w1.x; a0.y += x0.y * w1.y; a0.z += x0.y * w1.z; a0.w += x0.y * w1.w;
            a1.x += x1.y * w1.x; a1.y += x1.y * w1.y; a1.z += x1.y * w1.z; a1.w += x1.y * w1.w;
            a0.x += x0.z * w2.x; a0.y += x0.z * w2.y; a0.z += x0.z * w2.z; a0.w += x0.z * w2.w;
            a1.x += x1.z * w2.x; a1.y += x1.z * w2.y; a1.z += x1.z * w2.z; a1.w += x1.z * w2.w;
            a0.x += x0.w * w3.x; a0.y += x0.w * w3.y; a0.z += x0.w * w3.z; a0.w += x0.w * w3.w;
            a1.x += x1.w * w3.x; a1.y += x1.w * w3.y; a1.z += x1.w * w3.z; a1.w += x1.w * w3.w;
        }
        __syncthreads();
    }
    a0.x = leaky(a0.x); a0.y = leaky(a0.y); a0.z = leaky(a0.z); a0.w = leaky(a0.w);
    a1.x = leaky(a1.x); a1.y = leaky(a1.y); a1.z = leaky(a1.z); a1.w = leaky(a1.w);
    *reinterpret_cast<float4*>(Out + (long)r0 * 128 + jq * 4) = a0;
    *reinterpret_cast<float4*>(Out + (long)r1 * 128 + jq * 4) = a1;
}

__global__ __launch_bounds__(256) void gemmT_head_kernel(const void* In, const float* Wf, const float* Bf,
                                                         float* Out, const int* dflag) {
    if (*dflag) gemmT_body<float, C_IN, 40, 0>((const float*)In, nullptr, Wf, Bf, Out);
    else        gemmT_body<bf16,  C_IN, 40, 0>((const bf16*)In, nullptr, Wf, Bf, Out);
}

__global__ __launch_bounds__(256) void gemmT_tail_kernel(const float* InB, const float* InA,
                                                         const float* Wf, const float* Bf, float* Out) {
    gemmT_body<float, 192, 48, 1>(InB, InA, Wf, Bf, Out);
}

// ---------------- small GEMMs (N1/N2 scale): keep register version ----------------
template <typename T, int ACT>
__device__ __forceinline__ void gemm4_body(const T* __restrict__ In, const float* __restrict__ Wf,
                                           const float* __restrict__ Bf, float* __restrict__ Out,
                                           int Ci, int Co, int blk) {
    int tid = blk * 256 + threadIdx.x;
    int Coq = Co >> 2;
    int n = tid / Coq;
    int j4 = (tid - n * Coq) << 2;
    const T* in = In + (long)n * Ci;
    const float* wp = Wf + j4;
    float4 acc = *reinterpret_cast<const float4*>(Bf + j4);
    for (int c = 0; c < Ci; c += 4) {
        float4 xv = ld4(in, c);
        float4 w0 = *reinterpret_cast<const float4*>(wp + (long)c * Co);
        float4 w1 = *reinterpret_cast<const float4*>(wp + (long)(c + 1) * Co);
        float4 w2 = *reinterpret_cast<const float4*>(wp + (long)(c + 2) * Co);
        float4 w3 = *reinterpret_cast<const float4*>(wp + (long)(c + 3) * Co);
        acc.x += xv.x * w0.x; acc.y += xv.x * w0.y; acc.z += xv.x * w0.z; acc.w += xv.x * w0.w;
        acc.x += xv.y * w1.x; acc.y += xv.y * w1.y; acc.z += xv.y * w1.z; acc.w += xv.y * w1.w;
        acc.x += xv.z * w2.x; acc.y += xv.z * w2.y; acc.z += xv.z * w2.z; acc.w += xv.z * w2.w;
        acc.x += xv.w * w3.x; acc.y += xv.w * w3.y; acc.z += xv.w * w3.z; acc.w += xv.w * w3.w;
    }
    if (ACT) { acc.x = leaky(acc.x); acc.y = leaky(acc.y); acc.z = leaky(acc.z); acc.w = leaky(acc.w); }
    *reinterpret_cast<float4*>(Out + (long)n * Co + j4) = acc;
}

template <int ACT, int SPLIT>
__device__ __forceinline__ void gemm4cat_body(const float* __restrict__ InA, int sA,
                                              const float* __restrict__ InB, int sB,
                                              const float* __restrict__ Wf, const float* __restrict__ Bf,
                                              float* __restrict__ Out, int Ci, int Co, int blk) {
    int tid = blk * 256 + threadIdx.x;
    int Coq = Co >> 2;
    int n = tid / Coq;
    int j4 = (tid - n * Coq) << 2;
    const float* ia = InA + (long)(n >> 2) * sA;
    const float* ib = InB + (long)n * sB;
    const float* wp = Wf + j4;
    float4 acc = *reinterpret_cast<const float4*>(Bf + j4);
    for (int c = 0; c < Ci; c += 4) {
        float4 xv = (c < SPLIT) ? *reinterpret_cast<const float4*>(ia + c)
                                : *reinterpret_cast<const float4*>(ib + (c - SPLIT));
        float4 w0 = *reinterpret_cast<const float4*>(wp + (long)c * Co);
        float4 w1 = *reinterpret_cast<const float4*>(wp + (long)(c + 1) * Co);
        float4 w2 = *reinterpret_cast<const float4*>(wp + (long)(c + 2) * Co);
        float4 w3 = *reinterpret_cast<const float4*>(wp + (long)(c + 3) * Co);
        acc.x += xv.x * w0.x; acc.y += xv.x * w0.y; acc.z += xv.x * w0.z; acc.w += xv.x * w0.w;
        acc.x += xv.y * w1.x; acc.y += xv.y * w1.y; acc.z += xv.y * w1.z; acc.w += xv.y * w1.w;
        acc.x += xv.z * w2.x; acc.y += xv.z * w2.y; acc.z += xv.z * w2.z; acc.w += xv.z * w2.w;
        acc.x += xv.w * w3.x; acc.y += xv.w * w3.y; acc.z += xv.w * w3.z; acc.w += xv.w * w3.w;
    }
    if (ACT) { acc.x = leaky(acc.x); acc.y = leaky(acc.y); acc.z = leaky(acc.z); acc.w = leaky(acc.w); }
    *reinterpret_cast<float4*>(Out + (long)n * Co + j4) = acc;
}

__global__ __launch_bounds__(256) void gemm2_f32_kernel(const float* In,
                                                        const float* W1, const float* B1, float* O1, int Co1,
                                                        const float* W2, const float* B2, float* O2, int Co2,
                                                        int Ci, int nb1) {
    int b = blockIdx.x;
    if (b < nb1) gemm4_body<float, 0>(In, W1, B1, O1, Ci, Co1, b);
    else         gemm4_body<float, 0>(In, W2, B2, O2, Ci, Co2, b - nb1);
}

template <int SPLIT>
__global__ __launch_bounds__(256) void gemm2cat_kernel(const float* InA, int sA, const float* InB, int sB,
                                                       const float* W1, const float* B1, float* O1, int Co1,
                                                       const float* W2, const float* B2, float* O2, int Co2,
                                                       int Ci, int nb1) {
    int b = blockIdx.x;
    if (b < nb1) gemm4cat_body<0, SPLIT>(InA, sA, InB, sB, W1, B1, O1, Ci, Co1, b);
    else         gemm4cat_body<0, SPLIT>(InA, sA, InB, sB, W2, B2, O2, Ci, Co2, b - nb1);
}

// ---------------- depthwise 5x5 helpers ----------------
__device__ __forceinline__ void dw_load(const void* dwp, const void* dbp, float* wl, float* bl, int fl) {
    int t = threadIdx.x;
    for (int e = t; e < 25 * 128; e += 256) {
        int o = e / 25, i = e - o * 25;
        wl[i * 128 + o] = ldw(dwp, e, fl);
    }
    if (t < 128) bl[t] = ldw(dbp, t, fl);
}

__device__ __forceinline__ float4 dw_compute(int p, int o0, const float* __restrict__ In,
                                             const float* wl, const float* bl) {
    int h = p >> 7, w = p & 127;
    float4 acc = *reinterpret_cast<const float4*>(&bl[o0]);
#pragma unroll
    for (int dh = -2; dh <= 2; dh++) {
        int hh = h + dh;
        if ((unsigned)hh >= (unsigned)H_IMG) continue;
#pragma unroll
        for (int dv = -2; dv <= 2; dv++) {
            int ww = w + dv;
            if ((unsigned)ww >= (unsigned)W_IMG) continue;
            float4 iv = *reinterpret_cast<const float4*>(&In[(long)(((hh << 7) + ww) << 7) + o0]);
            float4 wv = *reinterpret_cast<const float4*>(&wl[((dh + 2) * 5 + (dv + 2)) * 128 + o0]);
            acc.x += iv.x * wv.x; acc.y += iv.y * wv.y; acc.z += iv.z * wv.z; acc.w += iv.w * wv.w;
        }
    }
    acc.x = leaky(acc.x); acc.y = leaky(acc.y); acc.z = leaky(acc.z); acc.w = leaky(acc.w);
    return acc;
}

// ---------------- S4: head dw + pool4 + e0 stats + tail raw stats ----------------
// grid 512; block covers 32 pixels (4 iters x 8 px); np = 512
__global__ __launch_bounds__(256) void dwpool_kernel(const float* __restrict__ In, const void* dwp, const void* dbp,
                                                     float* __restrict__ R1out, float* __restrict__ H1b,
                                                     float2* __restrict__ pE0, float2* __restrict__ pTb,
                                                     const int* dflag) {
    __shared__ float wl[25 * 128];
    __shared__ float bl[128];
    __shared__ float sm[8 * 132];
    int fl = *dflag;
    dw_load(dwp, dbp, wl, bl, fl);
    __syncthreads();
    int t = threadIdx.x;
    int o0 = (t & 31) << 2, pxl = t >> 5;
    float s = 0.f, s2 = 0.f, rs = 0.f, rs2 = 0.f;
    for (int it = 0; it < 4; it++) {
        int p = blockIdx.x * 32 + it * 8 + pxl;
        float4 acc = dw_compute(p, o0, In, wl, bl);
        *reinterpret_cast<float4*>(&R1out[(long)p * 128 + o0]) = acc;
        *reinterpret_cast<float4*>(&sm[pxl * 132 + o0]) = acc;
        __syncthreads();
        if (t < 128) {
#pragma unroll
            for (int g = 0; g < 2; g++) {
                float v0 = sm[(g * 4 + 0) * 132 + t], v1 = sm[(g * 4 + 1) * 132 + t];
                float v2 = sm[(g * 4 + 2) * 132 + t], v3 = sm[(g * 4 + 3) * 132 + t];
                float h = 0.25f * (v0 + v1 + v2 + v3);
                H1b[(long)(blockIdx.x * 8 + it * 2 + g) * 128 + t] = h;
                s += h; s2 += h * h;
                rs += v0 + v1 + v2 + v3;
                rs2 += v0 * v0 + v1 * v1 + v2 * v2 + v3 * v3;
            }
        }
        __syncthreads();
    }
    if (t < 128) {
        pE0[(long)t * 512 + blockIdx.x] = make_float2(s, s2);
        pTb[(long)t * 512 + blockIdx.x] = make_float2(rs, rs2);
    }
}

// ---------------- plain dw (not fused) not needed; tail dw fuses classifier ----------------
// S16: tail dw + classifier + softmax. grid 2048; block covers 8 px.
__global__ __launch_bounds__(256) void dwcls_kernel(const float* __restrict__ In, const void* dwp, const void* dbp,
                                                    const void* wsw, const void* wb, void* __restrict__ out,
                                                    const int* dflag) {
    __shared__ float wl[25 * 128];
    __shared__ float bl[128];
    __shared__ float cw[2048];
    __shared__ float F[8 * 132];
    int fl = *dflag;
    dw_load(dwp, dbp, wl, bl, fl);
    int t = threadIdx.x;
    for (int e = t; e < 2048; e += 256) cw[e] = ldw(wsw, e, fl);
    __syncthreads();
    int o0 = (t & 31) << 2, pxl = t >> 5;
    int p = blockIdx.x * 8 + pxl;
    float4 acc = dw_compute(p, o0, In, wl, bl);
    *reinterpret_cast<float4*>(&F[pxl * 132 + o0]) = acc;
    __syncthreads();
    if (t < 128) {
        int px = t >> 4, j = t & 15;
        float a = ldw(wb, j, fl);
        const float* fp = &F[px * 132];
#pragma unroll 8
        for (int c = 0; c < 128; c += 4) {
            float4 fv = *reinterpret_cast<const float4*>(fp + c);
            a += fv.x * cw[c * 16 + j] + fv.y * cw[(c + 1) * 16 + j]
               + fv.z * cw[(c + 2) * 16 + j] + fv.w * cw[(c + 3) * 16 + j];
        }
        float m = a;
#pragma unroll
        for (int s = 8; s > 0; s >>= 1) m = fmaxf(m, __shfl_xor(m, s, 16));
        float e = expf(a - m);
        float d = e;
#pragma unroll
        for (int s = 8; s > 0; s >>= 1) d += __shfl_xor(d, s, 16);
        float r = e / d;
        long oi = (long)(blockIdx.x * 8 + px) * 16 + j;
        if (fl) ((float*)out)[oi] = r;
        else ((bf16*)out)[oi] = __float2bfloat16(r);
    }
}

// ---------------- attention (4 rows/block) + fused pool/stat emission ----------------
template <int MODE>
__global__ __launch_bounds__(256) void attn_fused_kernel(const float* __restrict__ th, const float* __restrict__ outm,
                                                         const int* __restrict__ nbr, float* __restrict__ dst, int co,
                                                         float* __restrict__ H2b,
                                                         float2* __restrict__ partP, float2* __restrict__ partS,
                                                         int snp) {
    int wid = threadIdx.x >> 6, l = threadIdx.x & 63;
    int n = blockIdx.x * 4 + wid;
    float r0 = th[(long)n * 128 + l];
    float r1 = th[(long)n * 128 + 64 + l];
    int mk[KNB];
    float av[KNB];
#pragma unroll
    for (int k = 0; k < KNB; k++) {
        int m = nbr[n * KNB + k];
        mk[k] = m;
        float v = r0 * th[(long)m * 128 + l] + r1 * th[(long)m * 128 + 64 + l];
#pragma unroll
        for (int off = 32; off > 0; off >>= 1) v += __shfl_xor(v, off, 64);
        av[k] = 1.f / (1.f + expf(-v));
    }
    float amax = av[0];
#pragma unroll
    for (int k = 1; k < KNB; k++) amax = fmaxf(amax, av[k]);
    float den = 0.f;
#pragma unroll
    for (int k = 0; k < KNB; k++) { av[k] = expf(av[k] - amax); den += av[k]; }
    float rden = 1.f / den;
    float val = 0.f;
    if (l < co) {
        float acc = 0.f;
#pragma unroll
        for (int k = 0; k < KNB; k++) acc += av[k] * outm[(long)mk[k] * co + l];
        val = leaky(acc * rden);
        dst[(long)n * co + l] = val;
    }
    __shared__ float sm[4][64];
    sm[wid][l] = (l < co) ? val : 0.f;
    __syncthreads();
    if (wid == 0 && l < co) {
        float a = sm[0][l], bb = sm[1][l], c = sm[2][l], d = sm[3][l];
        float su = a + bb + c + d;
        float sq = a * a + bb * bb + c * c + d * d;
        if (MODE == 0) {
            float h = 0.25f * su;
            H2b[(long)blockIdx.x * 64 + l] = h;
            partP[(long)l * snp + blockIdx.x] = make_float2(h, h * h);
            partS[(long)l * snp + blockIdx.x] = make_float2(su, sq);
        } else {
            partS[(long)l * snp + blockIdx.x] = make_float2(4.f * su, 4.f * sq);
        }
    }
}

// ================= host side =================
extern "C" void kernel_launch(void* const* d_in, const int* in_sizes, int n_in,
                              void* d_out, int out_size, void* d_ws, size_t ws_size,
                              hipStream_t stream) {
    bool dict = (in_sizes[1] > 1000000);
    int I_x, I_nbr_a, I_nbr_b, I_hg, I_ws, I_e0, I_e1, I_d0, I_tg;
    if (dict) {
        I_x = 0; I_nbr_a = 5; I_nbr_b = 6; I_hg = 7; I_e0 = 13; I_e1 = 19; I_d0 = 25; I_tg = 31; I_ws = 37;
    } else {
        I_x = 0; I_hg = 1; I_e0 = 7; I_e1 = 13; I_d0 = 19; I_tg = 25; I_ws = 31; I_nbr_a = 37; I_nbr_b = 38;
    }
    const void* x    = d_in[I_x];
    const int* nbr_a = (const int*)d_in[I_nbr_a];
    const int* nbr_b = (const int*)d_in[I_nbr_b];
    const void* hg   = d_in[I_hg + 0];
    const void* hb   = d_in[I_hg + 1];
    const void* hpw  = d_in[I_hg + 2];
    const void* hpb  = d_in[I_hg + 3];
    const void* hdw  = d_in[I_hg + 4];
    const void* hdb  = d_in[I_hg + 5];
    const void* e0_g = d_in[I_e0 + 0];
    const void* e0_b = d_in[I_e0 + 1];
    const void* e0_wt= d_in[I_e0 + 2];
    const void* e0_bt= d_in[I_e0 + 3];
    const void* e0_wo= d_in[I_e0 + 4];
    const void* e0_bo= d_in[I_e0 + 5];
    const void* e1_g = d_in[I_e1 + 0];
    const void* e1_b = d_in[I_e1 + 1];
    const void* e1_wt= d_in[I_e1 + 2];
    const void* e1_bt= d_in[I_e1 + 3];
    const void* e1_wo= d_in[I_e1 + 4];
    const void* e1_bo= d_in[I_e1 + 5];
    const void* d0_g = d_in[I_d0 + 0];
    const void* d0_b = d_in[I_d0 + 1];
    const void* d0_wt= d_in[I_d0 + 2];
    const void* d0_bt= d_in[I_d0 + 3];
    const void* d0_wo= d_in[I_d0 + 4];
    const void* d0_bo= d_in[I_d0 + 5];
    const void* tg   = d_in[I_tg + 0];
    const void* tb   = d_in[I_tg + 1];
    const void* tpw  = d_in[I_tg + 2];
    const void* tpb  = d_in[I_tg + 3];
    const void* tdw  = d_in[I_tg + 4];
    const void* tdb  = d_in[I_tg + 5];
    const void* wsw  = d_in[I_ws + 0];
    const void* wb   = d_in[I_ws + 1];

    float* W = (float*)d_ws;
    float*  WF1    = W + 0;                   // 200*128
    float*  BF1    = W + 25600;
    float*  WF2    = W + 25728;               // 128*64
    float*  BF2    = W + 33920;
    int*    dflag  = (int*)(W + 33984);
    float2* P_HEAD = (float2*)(W + 34048);    // 200 x 256
    float2* P_E0   = (float2*)(W + 136448);   // 128 x 512
    float2* P_Tb   = (float2*)(W + 267520);   // 128 x 512
    float2* P_E1   = (float2*)(W + 398592);   // 64 x 1024
    float2* P_D0a  = (float2*)(W + 529664);   // 32 x 256
    float2* P_D0b  = (float2*)(W + 546048);   // 64 x 1024
    float2* P_Ta   = (float2*)(W + 677120);   // 64 x 1024
    float*  R0     = W + 808192;              // 16384*128
    float*  R1     = R0 + (long)N0 * 128;     // 16384*128 (enc0)
    float*  T1     = R1 + (long)N0 * 128;     // 16384*128
    float*  H1b    = T1 + (long)N0 * 128;     // 4096*128
    float*  THb    = H1b + (long)N1 * 128;    // 4096*128
    float*  OUTb   = THb + (long)N1 * 128;    // 4096*64
    float*  ENC1   = OUTb + (long)N1 * 64;    // 4096*64
    float*  H2b    = ENC1 + (long)N1 * 64;    // 1024*64
    float*  HDb    = H2b + (long)N2 * 64;     // 1024*32
    float*  HDEC   = HDb + (long)N2 * 32;     // 4096*64

    // 1. head BN stage A (+ detect)
    bnx_kernel<<<256, 256, 0, stream>>>(x, P_HEAD, dflag);
    // 2. head BN reduce + fold 1x1 (omajor)
    bnfold_kernel<<<128, 256, 0, stream>>>(P_HEAD, 256, C_IN, P_HEAD, 256, N0,
                                           hg, hb, hpw, hpb, WF1, BF1, C_IN, 128, 1, dflag);
    // 3. head pointwise GEMM (LDS-tiled) + leaky
    gemmT_head_kernel<<<1024, 256, 0, stream>>>(x, WF1, BF1, R0, dflag);
    // 4. head dw + pool4 + e0/tail stats
    dwpool_kernel<<<512, 256, 0, stream>>>(R0, hdw, hdb, R1, H1b, P_E0, P_Tb, dflag);
    // 5. e0 BN reduce + fold wt/wo
    bnfold2_kernel<<<192, 256, 0, stream>>>(P_E0, 512, 128, P_E0, 512, N1, e0_g, e0_b,
                                            e0_wt, e0_bt, e0_wo, e0_bo,
                                            WF1, BF1, WF2, BF2, 128, 128, 64, dflag);
    // 6. e0 theta+out GEMMs
    gemm2_f32_kernel<<<768, 256, 0, stream>>>(H1b, WF1, BF1, THb, 128, WF2, BF2, OUTb, 64, 128, 512);
    // 7. e0 attention -> ENC1 (+H2b, e1 stats, d0 stats ch32..95)
    attn_fused_kernel<0><<<1024, 256, 0, stream>>>(THb, OUTb, nbr_a, ENC1, 64, H2b, P_E1, P_D0b, 1024);
    // 8. e1 BN reduce + fold
    bnfold2_kernel<<<160, 256, 0, stream>>>(P_E1, 1024, 64, P_E1, 1024, N2, e1_g, e1_b,
                                            e1_wt, e1_bt, e1_wo, e1_bo,
                                            WF1, BF1, WF2, BF2, 64, 128, 32, dflag);
    // 9. e1 GEMMs
    gemm2_f32_kernel<<<160, 256, 0, stream>>>(H2b, WF1, BF1, THb, 128, WF2, BF2, OUTb, 32, 64, 128);
    // 10. e1 attention -> HDb (+d0 stats ch0..31, x4)
    attn_fused_kernel<1><<<256, 256, 0, stream>>>(THb, OUTb, nbr_b, HDb, 32, nullptr, nullptr, P_D0a, 256);
    // 11. d0 BN reduce + fold
    bnfold2_kernel<<<192, 256, 0, stream>>>(P_D0a, 256, 32, P_D0b, 1024, N1, d0_g, d0_b,
                                            d0_wt, d0_bt, d0_wo, d0_bo,
                                            WF1, BF1, WF2, BF2, 96, 128, 64, dflag);
    // 12. d0 GEMMs on virtual concat [HDb | ENC1]
    gemm2cat_kernel<32><<<768, 256, 0, stream>>>(HDb, 32, ENC1, 64,
                                                 WF1, BF1, THb, 128, WF2, BF2, OUTb, 64, 96, 512);
    // 13. d0 attention -> HDEC (+tail stats ch0..63, x4)
    attn_fused_kernel<2><<<1024, 256, 0, stream>>>(THb, OUTb, nbr_a, HDEC, 64, nullptr, nullptr, P_Ta, 1024);
    // 14. tail BN reduce + fold (omajor)
    bnfold_kernel<<<128, 256, 0, stream>>>(P_Ta, 1024, 64, P_Tb, 512, N0,
                                           tg, tb, tpw, tpb, WF1, BF1, 192, 128, 1, dflag);
    // 15. tail pointwise GEMM (LDS-tiled) + leaky on virtual concat [HDEC | enc0]
    gemmT_tail_kernel<<<1024, 256, 0, stream>>>(R1, HDEC, WF1, BF1, T1);
    // 16. tail dw + classifier + softmax
    dwcls_kernel<<<2048, 256, 0, stream>>>(T1, tdw, tdb, wsw, wb, d_out, dflag);
}